// Round 2
// baseline (347.839 us; speedup 1.0000x reference)
//
#include <hip/hip_runtime.h>
#include <hip/hip_bf16.h>
#include <math.h>

// CovidModel forward, closed form:
//   A[d][s]  = wA[s] * 2^(L[d] / T_serial[s]),  L[d] = prefix sum of log2 r[0..d]
//   M[d][s]  = rho[s] * sum_j pi[j][s] * A_ext[J+d-j-1][s]
// Rescale: Ã = A / wA, pis[j] = rho*wA*pi[j]  →  M = sum_j pis[j]*Ã[d-1-j],
// and Ã[d] = exp2f(L[d]*invT) — one v_exp_f32 per (day,sample).
// Kernel 1: length-T prefix sum of log2 r (double accum, single block).
// Kernel 2: thread = one sample × one 120-day chunk; compile-time rotated
//           10-register window (unroll by J → zero register shuffling),
//           nontemporal stores (out is a pure write stream).

#define SCAN_THREADS 1024

__global__ void prefix_log2_kernel(const float* __restrict__ r,
                                   float* __restrict__ L,
                                   int T, int chunk) {
    __shared__ double ssum[SCAN_THREADS];
    const int t = threadIdx.x;
    const int begin = t * chunk;
    const int end = min(begin + chunk, T);

    double local = 0.0;
    for (int i = begin; i < end; ++i) local += (double)log2f(r[i]);
    ssum[t] = local;
    __syncthreads();

    for (int off = 1; off < SCAN_THREADS; off <<= 1) {
        double v = (t >= off) ? ssum[t - off] : 0.0;
        __syncthreads();
        ssum[t] += v;
        __syncthreads();
    }

    double run = (t == 0) ? 0.0 : ssum[t - 1];   // exclusive prefix
    for (int i = begin; i < end; ++i) {
        run += (double)log2f(r[i]);
        L[i] = (float)run;                        // inclusive prefix, fp32
    }
}

template <int J>
__global__ void forecast_kernel(const float* __restrict__ L,
                                const float* __restrict__ warmup_A,
                                const float* __restrict__ T_serial,
                                const float* __restrict__ rho_M,
                                const float* __restrict__ pi_M,
                                float* __restrict__ out,
                                int T, int S, int dchunk) {
    const int s = blockIdx.x * blockDim.x + threadIdx.x;
    if (s >= S) return;

    const int d0   = blockIdx.y * dchunk;
    const int dend = min(d0 + dchunk, T);

    const float invT = 1.0f / T_serial[s];
    const float wA   = warmup_A[(J - 1) * S + s];
    const float scl  = rho_M[s] * wA;
    const float invW = 1.0f / wA;

    float pis[J];
#pragma unroll
    for (int j = 0; j < J; ++j) pis[j] = pi_M[j * S + s] * scl;

    // Invariant at group start db: a[i] = Ã[db - J + i], i = 0..J-1.
    float a[J];
#pragma unroll
    for (int i = 0; i < J; ++i) {
        const int t = d0 - J + i;
        a[i] = (t >= 0) ? exp2f(L[t] * invT)
                        : warmup_A[(J + t) * S + s] * invW;
    }

    for (int db = d0; db < dend; db += J) {
#pragma unroll
        for (int k = 0; k < J; ++k) {
            const int d = db + k;
            if (d < dend) {
                float m = 0.0f;
#pragma unroll
                for (int j = 0; j < J; ++j)
                    m = fmaf(pis[j], a[(J + k - 1 - j) % J], m);  // compile-time slot
                __builtin_nontemporal_store(m, &out[(size_t)d * S + s]);
                a[k] = exp2f(L[d] * invT);   // Ã[db+k] → slot k (after use)
            }
        }
    }
}

extern "C" void kernel_launch(void* const* d_in, const int* in_sizes, int n_in,
                              void* d_out, int out_size, void* d_ws, size_t ws_size,
                              hipStream_t stream) {
    const float* r_t      = (const float*)d_in[0];   // (1, T)
    const float* warmup_A = (const float*)d_in[1];   // (J, S)
    const float* T_serial = (const float*)d_in[2];   // (S,)
    const float* rho_M    = (const float*)d_in[3];   // (S,)
    const float* pi_M     = (const float*)d_in[4];   // (J, S)
    float* out            = (float*)d_out;           // (T, S)

    const int T = in_sizes[0];
    const int S = in_sizes[2];

    float* L = (float*)d_ws;                          // T floats of scratch

    const int chunk = (T + SCAN_THREADS - 1) / SCAN_THREADS;
    prefix_log2_kernel<<<1, SCAN_THREADS, 0, stream>>>(r_t, L, T, chunk);

    const int dchunk = 120;                           // multiple of J=10
    dim3 block(256, 1, 1);
    dim3 grid((S + 255) / 256, (T + dchunk - 1) / dchunk, 1);
    forecast_kernel<10><<<grid, block, 0, stream>>>(L, warmup_A, T_serial, rho_M,
                                                    pi_M, out, T, S, dchunk);
}

// Round 4
// 228.086 us; speedup vs baseline: 1.5250x; 1.5250x over previous
//
#include <hip/hip_runtime.h>
#include <hip/hip_bf16.h>
#include <math.h>

// CovidModel forward, closed form:
//   A[d][s] = wA[s] * 2^(L[d]/T_serial[s]),  L[d] = inclusive prefix of log2 r
//   M[d][s] = rho[s] * sum_j pi[j][s] * A_ext[J+d-j-1][s]
// Rescaled: Ã = A/wA, pis[j] = rho*wA*pi[j] → M = Σ_j pis[j]·Ã[d-1-j],
// Ã[d] = exp2f(L[d]·invT): one v_exp_f32 per (day,sample).
//
// Scan = 3 parallel kernels (fp64): per-block inclusive scan → one-wave scan
// of block totals → add offsets, emit fp32 L.
// Forecast: thread = 4 samples × 50-day chunk; float4 NT stores (ext_vector
// type — HIP float4 is a class and rejected by the builtin), one L[d] load
// per 4 outputs, compile-time rotated 10-register window.

#define SCAN_BS 1024

typedef float v4f __attribute__((ext_vector_type(4)));

__global__ void scan_blocks_kernel(const float* __restrict__ r, int T,
                                   double* __restrict__ Lpart,
                                   double* __restrict__ blockSums) {
    __shared__ double sh[SCAN_BS];
    const int i = blockIdx.x * SCAN_BS + threadIdx.x;
    double v = (i < T) ? (double)log2f(r[i]) : 0.0;
    sh[threadIdx.x] = v;
    __syncthreads();
    for (int off = 1; off < SCAN_BS; off <<= 1) {
        double u = (threadIdx.x >= off) ? sh[threadIdx.x - off] : 0.0;
        __syncthreads();
        sh[threadIdx.x] += u;
        __syncthreads();
    }
    if (i < T) Lpart[i] = sh[threadIdx.x];
    if (threadIdx.x == SCAN_BS - 1) blockSums[blockIdx.x] = sh[SCAN_BS - 1];
}

__global__ void scan_sums_kernel(const double* __restrict__ blockSums, int nb,
                                 double* __restrict__ offsets) {
    const int lane = threadIdx.x;            // 64 threads, nb <= 64
    double v = (lane < nb) ? blockSums[lane] : 0.0;
    for (int off = 1; off < 64; off <<= 1) {
        double u = __shfl_up(v, (unsigned)off, 64);
        if (lane >= off) v += u;
    }
    double excl = __shfl_up(v, 1u, 64);
    if (lane == 0) excl = 0.0;
    if (lane < nb) offsets[lane] = excl;
}

__global__ void scan_apply_kernel(const double* __restrict__ Lpart,
                                  const double* __restrict__ offsets,
                                  float* __restrict__ L, int T) {
    const int i = blockIdx.x * SCAN_BS + threadIdx.x;
    if (i < T) L[i] = (float)(Lpart[i] + offsets[blockIdx.x]);
}

template <int J>
__global__ void forecast4_kernel(const float* __restrict__ L,
                                 const float* __restrict__ warmup_A,
                                 const float* __restrict__ T_serial,
                                 const float* __restrict__ rho_M,
                                 const float* __restrict__ pi_M,
                                 float* __restrict__ out,
                                 int T, int S, int dchunk) {
    const int q = blockIdx.x * blockDim.x + threadIdx.x;
    const int s = q * 4;
    if (s + 3 >= S) return;                  // full quads only (tail via scalar kernel)

    const int d0   = blockIdx.y * dchunk;
    const int dend = min(d0 + dchunk, T);

    const float4 ts  = *reinterpret_cast<const float4*>(&T_serial[s]);
    const float4 rho = *reinterpret_cast<const float4*>(&rho_M[s]);
    const float4 wA4 = *reinterpret_cast<const float4*>(&warmup_A[(J - 1) * S + s]);

    float invT[4] = {1.f / ts.x, 1.f / ts.y, 1.f / ts.z, 1.f / ts.w};
    float wA[4]   = {wA4.x, wA4.y, wA4.z, wA4.w};
    float scl[4]  = {rho.x * wA[0], rho.y * wA[1], rho.z * wA[2], rho.w * wA[3]};
    float invW[4] = {1.f / wA[0], 1.f / wA[1], 1.f / wA[2], 1.f / wA[3]};

    float pis[J][4];
#pragma unroll
    for (int j = 0; j < J; ++j) {
        const float4 p = *reinterpret_cast<const float4*>(&pi_M[j * S + s]);
        pis[j][0] = p.x * scl[0]; pis[j][1] = p.y * scl[1];
        pis[j][2] = p.z * scl[2]; pis[j][3] = p.w * scl[3];
    }

    // Invariant at group start db: a[i][c] = Ã[db - J + i], i = 0..J-1.
    float a[J][4];
#pragma unroll
    for (int i = 0; i < J; ++i) {
        const int t = d0 - J + i;
        if (t >= 0) {
            const float Lt = L[t];
#pragma unroll
            for (int c = 0; c < 4; ++c) a[i][c] = exp2f(Lt * invT[c]);
        } else {
            const float4 w = *reinterpret_cast<const float4*>(&warmup_A[(J + t) * S + s]);
            a[i][0] = w.x * invW[0]; a[i][1] = w.y * invW[1];
            a[i][2] = w.z * invW[2]; a[i][3] = w.w * invW[3];
        }
    }

    for (int db = d0; db < dend; db += J) {
#pragma unroll
        for (int k = 0; k < J; ++k) {
            const int d = db + k;
            if (d < dend) {
                float m[4] = {0.f, 0.f, 0.f, 0.f};
#pragma unroll
                for (int j = 0; j < J; ++j) {
                    const int slot = (J + k - 1 - j) % J;    // compile-time
#pragma unroll
                    for (int c = 0; c < 4; ++c) m[c] = fmaf(pis[j][c], a[slot][c], m[c]);
                }
                v4f mv;
                mv.x = m[0]; mv.y = m[1]; mv.z = m[2]; mv.w = m[3];
                __builtin_nontemporal_store(mv,
                    reinterpret_cast<v4f*>(&out[(size_t)d * S + s]));
                const float Ld = L[d];
#pragma unroll
                for (int c = 0; c < 4; ++c) a[k][c] = exp2f(Ld * invT[c]);
            }
        }
    }
}

template <int J>
__global__ void forecast_scalar_kernel(const float* __restrict__ L,
                                       const float* __restrict__ warmup_A,
                                       const float* __restrict__ T_serial,
                                       const float* __restrict__ rho_M,
                                       const float* __restrict__ pi_M,
                                       float* __restrict__ out,
                                       int T, int S, int s0, int dchunk) {
    const int s = s0 + blockIdx.x * blockDim.x + threadIdx.x;
    if (s >= S) return;
    const int d0   = blockIdx.y * dchunk;
    const int dend = min(d0 + dchunk, T);

    const float invT = 1.0f / T_serial[s];
    const float wA   = warmup_A[(J - 1) * S + s];
    const float scl  = rho_M[s] * wA;
    const float invW = 1.0f / wA;

    float pis[J];
#pragma unroll
    for (int j = 0; j < J; ++j) pis[j] = pi_M[j * S + s] * scl;

    float a[J];
#pragma unroll
    for (int i = 0; i < J; ++i) {
        const int t = d0 - J + i;
        a[i] = (t >= 0) ? exp2f(L[t] * invT)
                        : warmup_A[(J + t) * S + s] * invW;
    }
    for (int db = d0; db < dend; db += J) {
#pragma unroll
        for (int k = 0; k < J; ++k) {
            const int d = db + k;
            if (d < dend) {
                float m = 0.0f;
#pragma unroll
                for (int j = 0; j < J; ++j) m = fmaf(pis[j], a[(J + k - 1 - j) % J], m);
                __builtin_nontemporal_store(m, &out[(size_t)d * S + s]);
                a[k] = exp2f(L[d] * invT);
            }
        }
    }
}

extern "C" void kernel_launch(void* const* d_in, const int* in_sizes, int n_in,
                              void* d_out, int out_size, void* d_ws, size_t ws_size,
                              hipStream_t stream) {
    const float* r_t      = (const float*)d_in[0];   // (1, T)
    const float* warmup_A = (const float*)d_in[1];   // (J, S)
    const float* T_serial = (const float*)d_in[2];   // (S,)
    const float* rho_M    = (const float*)d_in[3];   // (S,)
    const float* pi_M     = (const float*)d_in[4];   // (J, S)
    float* out            = (float*)d_out;           // (T, S)

    const int T = in_sizes[0];
    const int S = in_sizes[2];
    const int nb = (T + SCAN_BS - 1) / SCAN_BS;      // 49 for T=50000 (<=64)

    // Workspace layout
    char* ws = (char*)d_ws;
    double* Lpart   = (double*)ws;                        // T doubles
    double* bsums   = (double*)(ws + ((size_t)T * 8 + 255) / 256 * 256);
    double* offsets = bsums + 64;
    float*  L       = (float*)(offsets + 64);             // T floats

    scan_blocks_kernel<<<nb, SCAN_BS, 0, stream>>>(r_t, T, Lpart, bsums);
    scan_sums_kernel<<<1, 64, 0, stream>>>(bsums, nb, offsets);
    scan_apply_kernel<<<nb, SCAN_BS, 0, stream>>>(Lpart, offsets, L, T);

    const int dchunk = 50;                            // multiple of J=10
    const int quads = S / 4;
    if (quads > 0) {
        dim3 block(256, 1, 1);
        dim3 grid((quads + 255) / 256, (T + dchunk - 1) / dchunk, 1);
        forecast4_kernel<10><<<grid, block, 0, stream>>>(L, warmup_A, T_serial,
                                                         rho_M, pi_M, out, T, S, dchunk);
    }
    const int tail = S - quads * 4;
    if (tail > 0) {
        dim3 block(64, 1, 1);
        dim3 grid(1, (T + dchunk - 1) / dchunk, 1);
        forecast_scalar_kernel<10><<<grid, block, 0, stream>>>(L, warmup_A, T_serial,
                                                               rho_M, pi_M, out, T, S,
                                                               quads * 4, dchunk);
    }
}